// Round 1
// baseline (980.055 us; speedup 1.0000x reference)
//
#include <hip/hip_runtime.h>

#define N_NODES   100000
#define N_EDGES   1600000
#define NUM_GRAPHS 128
#define HID       64

// ---------------------------------------------------------------- utilities

__device__ __forceinline__ int wave_incl_scan(int v, int lane) {
  #pragma unroll
  for (int d = 1; d < 64; d <<= 1) {
    int t = __shfl_up(v, d, 64);
    if (lane >= d) v += t;
  }
  return v;
}

__global__ void k_zero(int* __restrict__ p, int n) {
  int i = blockIdx.x * blockDim.x + threadIdx.x;
  if (i < n) p[i] = 0;
}

// ---------------------------------------------------------------- CSR build

__global__ void k_count(const int* __restrict__ dst, int* __restrict__ counts) {
  int e = blockIdx.x * blockDim.x + threadIdx.x;
  if (e < N_EDGES) atomicAdd(&counts[dst[e]], 1);
}

__global__ void k_dinv(const int* __restrict__ counts, float* __restrict__ dinv) {
  int v = blockIdx.x * blockDim.x + threadIdx.x;
  if (v < N_NODES) dinv[v] = rsqrtf((float)(counts[v] + 1));  // +1 self-loop
}

// Non-monotone CSR allocation: each wave does ONE atomicAdd of its chunk sum,
// then distributes per-node offsets via the inclusive scan.
__global__ void k_alloc(const int* __restrict__ counts, int* __restrict__ row_off,
                        int* __restrict__ total) {
  int i = blockIdx.x * blockDim.x + threadIdx.x;
  int lane = threadIdx.x & 63;
  int c = (i < N_NODES) ? counts[i] : 0;
  int incl = wave_incl_scan(c, lane);
  int base = 0;
  if (lane == 63) base = atomicAdd(total, incl);
  base = __shfl(base, 63, 64);
  if (i < N_NODES) row_off[i] = base + incl - c;
}

__global__ void k_fill(const int* __restrict__ src, const int* __restrict__ dst,
                       const float* __restrict__ dinv, const int* __restrict__ row_off,
                       int* __restrict__ fill_cnt, int2* __restrict__ csr) {
  int e = blockIdx.x * blockDim.x + threadIdx.x;
  if (e >= N_EDGES) return;
  int s = src[e], d = dst[e];
  int p = atomicAdd(&fill_cnt[d], 1);
  int j = row_off[d] + p;
  csr[j] = make_int2(s, __float_as_int(dinv[s] * dinv[d]));
}

// ---------------------------------------------------------------- dense GEMM
// C[100000,64] = A[100000,64] @ W[64,64]. 64-row tile per 256-thread block.

__global__ __launch_bounds__(256) void k_gemm(const float* __restrict__ A,
                                              const float* __restrict__ W,
                                              float* __restrict__ C) {
  __shared__ float sW[64 * 64];
  __shared__ float sA[64][65];  // +1 pad: kills stride-64 bank conflicts
  int tid = threadIdx.x;
  #pragma unroll
  for (int i = tid; i < 1024; i += 256)
    ((float4*)sW)[i] = ((const float4*)W)[i];
  long row0 = (long)blockIdx.x * 64;
  #pragma unroll
  for (int i = tid; i < 1024; i += 256) {
    int r = i >> 4, c4 = (i & 15) << 2;
    long row = row0 + r;
    float4 v = (row < N_NODES) ? *(const float4*)(A + row * 64 + c4)
                               : make_float4(0.f, 0.f, 0.f, 0.f);
    sA[r][c4 + 0] = v.x; sA[r][c4 + 1] = v.y; sA[r][c4 + 2] = v.z; sA[r][c4 + 3] = v.w;
  }
  __syncthreads();
  int tr = (tid >> 4) << 2;   // 4 rows per thread
  int tc = (tid & 15) << 2;   // 4 cols per thread
  float acc[4][4];
  #pragma unroll
  for (int i = 0; i < 4; ++i)
    #pragma unroll
    for (int j = 0; j < 4; ++j) acc[i][j] = 0.f;
  #pragma unroll 8
  for (int k = 0; k < 64; ++k) {
    float4 w = *(const float4*)&sW[k * 64 + tc];
    float a0 = sA[tr + 0][k], a1 = sA[tr + 1][k], a2 = sA[tr + 2][k], a3 = sA[tr + 3][k];
    acc[0][0] += a0 * w.x; acc[0][1] += a0 * w.y; acc[0][2] += a0 * w.z; acc[0][3] += a0 * w.w;
    acc[1][0] += a1 * w.x; acc[1][1] += a1 * w.y; acc[1][2] += a1 * w.z; acc[1][3] += a1 * w.w;
    acc[2][0] += a2 * w.x; acc[2][1] += a2 * w.y; acc[2][2] += a2 * w.z; acc[2][3] += a2 * w.w;
    acc[3][0] += a3 * w.x; acc[3][1] += a3 * w.y; acc[3][2] += a3 * w.z; acc[3][3] += a3 * w.w;
  }
  #pragma unroll
  for (int i = 0; i < 4; ++i) {
    long row = row0 + tr + i;
    if (row < N_NODES)
      *(float4*)(C + row * 64 + tc) = make_float4(acc[i][0], acc[i][1], acc[i][2], acc[i][3]);
  }
}

// ---------------------------------------------------------------- aggregation
// out[v] = relu( dinv[v]^2 * hw[v] + sum_{e: dst=v} norm_e * hw[src_e] + b )
// One wave per node; lane = feature.

__global__ __launch_bounds__(256) void k_agg(const float* __restrict__ hw,
                                             const int* __restrict__ row_off,
                                             const int* __restrict__ counts,
                                             const int2* __restrict__ csr,
                                             const float* __restrict__ dinv,
                                             const float* __restrict__ bias,
                                             float* __restrict__ out) {
  int wid = threadIdx.x >> 6;
  int lane = threadIdx.x & 63;
  int v = blockIdx.x * (blockDim.x >> 6) + wid;
  if (v >= N_NODES) return;
  float dv = dinv[v];
  float acc = dv * dv * hw[(size_t)v * HID + lane];
  int o = row_off[v], c = counts[v];
  int i = 0;
  for (; i + 4 <= c; i += 4) {
    int2 p0 = csr[o + i + 0];
    int2 p1 = csr[o + i + 1];
    int2 p2 = csr[o + i + 2];
    int2 p3 = csr[o + i + 3];
    float h0 = hw[(size_t)p0.x * HID + lane];
    float h1 = hw[(size_t)p1.x * HID + lane];
    float h2 = hw[(size_t)p2.x * HID + lane];
    float h3 = hw[(size_t)p3.x * HID + lane];
    acc += __int_as_float(p0.y) * h0;
    acc += __int_as_float(p1.y) * h1;
    acc += __int_as_float(p2.y) * h2;
    acc += __int_as_float(p3.y) * h3;
  }
  for (; i < c; ++i) {
    int2 p = csr[o + i];
    acc += __int_as_float(p.y) * hw[(size_t)p.x * HID + lane];
  }
  out[(size_t)v * HID + lane] = fmaxf(acc + bias[lane], 0.0f);
}

// ---------------------------------------------------------------- pooling + MLP

__global__ __launch_bounds__(256) void k_pool(const float* __restrict__ h,
                                              const int* __restrict__ batch,
                                              float* __restrict__ pooled,
                                              int* __restrict__ pcnt) {
  int wid = threadIdx.x >> 6, lane = threadIdx.x & 63;
  int v = blockIdx.x * (blockDim.x >> 6) + wid;
  if (v >= N_NODES) return;
  int g = batch[v];
  atomicAdd(&pooled[g * HID + lane], h[(size_t)v * HID + lane]);
  if (lane == 0) atomicAdd(&pcnt[g], 1);
}

__global__ void k_mlp(const float* __restrict__ pooled, const int* __restrict__ pcnt,
                      const float* __restrict__ fc1w, const float* __restrict__ fc1b,
                      const float* __restrict__ fc2w, const float* __restrict__ fc2b,
                      float* __restrict__ out) {
  int g = threadIdx.x;
  if (g >= NUM_GRAPHS) return;
  float inv = 1.0f / fmaxf((float)pcnt[g], 1.0f);
  float hid[10];
  #pragma unroll
  for (int j = 0; j < 10; ++j) hid[j] = fc1b[j];
  for (int k = 0; k < HID; ++k) {
    float p = pooled[g * HID + k] * inv;
    #pragma unroll
    for (int j = 0; j < 10; ++j) hid[j] += p * fc1w[k * 10 + j];
  }
  float o = fc2b[0];
  #pragma unroll
  for (int j = 0; j < 10; ++j) o += fmaxf(hid[j], 0.0f) * fc2w[j];
  out[g] = o;
}

// ---------------------------------------------------------------- launch

extern "C" void kernel_launch(void* const* d_in, const int* in_sizes, int n_in,
                              void* d_out, int out_size, void* d_ws, size_t ws_size,
                              hipStream_t stream) {
  const float* x    = (const float*)d_in[0];
  const int*   ei   = (const int*)d_in[1];      // [2, E]
  const int*   batch= (const int*)d_in[2];
  const float* W1   = (const float*)d_in[3];
  const float* b1   = (const float*)d_in[4];
  const float* W2   = (const float*)d_in[5];
  const float* b2   = (const float*)d_in[6];
  const float* W3   = (const float*)d_in[7];
  const float* b3   = (const float*)d_in[8];
  const float* fc1w = (const float*)d_in[9];
  const float* fc1b = (const float*)d_in[10];
  const float* fc2w = (const float*)d_in[11];
  const float* fc2b = (const float*)d_in[12];

  const int* e_src = ei;
  const int* e_dst = ei + N_EDGES;

  // workspace layout
  char* ws = (char*)d_ws;
  int* counts   = (int*)ws;                  // [100000]
  int* fill_cnt = counts + 100000;           // [100000]
  int* total    = counts + 200000;           // [1] (+pad to 64)
  int* pcnt     = counts + 200064;           // [128]
  float* pooled = (float*)(counts + 200192); // [8192]
  const int ZERO_N = 208384;                 // everything above, in ints
  size_t off = (size_t)ZERO_N * 4;
  auto alignup = [](size_t o, size_t a) { return (o + a - 1) / a * a; };
  off = alignup(off, 256);
  float* dinv = (float*)(ws + off);  off += (size_t)N_NODES * 4;   off = alignup(off, 256);
  int* row_off = (int*)(ws + off);   off += (size_t)N_NODES * 4;   off = alignup(off, 256);
  int2* csr = (int2*)(ws + off);     off += (size_t)N_EDGES * 8;   off = alignup(off, 256);
  float* h_a = (float*)(ws + off);   off += (size_t)N_NODES * HID * 4; off = alignup(off, 256);
  float* h_b = (float*)(ws + off);   off += (size_t)N_NODES * HID * 4;
  (void)ws_size; (void)in_sizes; (void)n_in; (void)out_size;

  const int TB = 256;
  // CSR build
  k_zero <<<(ZERO_N + TB - 1) / TB, TB, 0, stream>>>(counts, ZERO_N);
  k_count<<<(N_EDGES + TB - 1) / TB, TB, 0, stream>>>(e_dst, counts);
  k_dinv <<<(N_NODES + TB - 1) / TB, TB, 0, stream>>>(counts, dinv);
  k_alloc<<<(N_NODES + TB - 1) / TB, TB, 0, stream>>>(counts, row_off, total);
  k_fill <<<(N_EDGES + TB - 1) / TB, TB, 0, stream>>>(e_src, e_dst, dinv, row_off, fill_cnt, csr);

  const int GEMM_GRID = (N_NODES + 63) / 64;       // 1563
  const int AGG_GRID  = (N_NODES + 3) / 4;         // 25000 (4 waves/block)

  // layer 1
  k_gemm<<<GEMM_GRID, TB, 0, stream>>>(x, W1, h_a);
  k_agg <<<AGG_GRID, TB, 0, stream>>>(h_a, row_off, counts, csr, dinv, b1, h_b);
  // layer 2
  k_gemm<<<GEMM_GRID, TB, 0, stream>>>(h_b, W2, h_a);
  k_agg <<<AGG_GRID, TB, 0, stream>>>(h_a, row_off, counts, csr, dinv, b2, h_b);
  // layer 3
  k_gemm<<<GEMM_GRID, TB, 0, stream>>>(h_b, W3, h_a);
  k_agg <<<AGG_GRID, TB, 0, stream>>>(h_a, row_off, counts, csr, dinv, b3, h_b);

  // pool + MLP
  k_pool<<<AGG_GRID, TB, 0, stream>>>(h_b, batch, pooled, pcnt);
  k_mlp <<<1, 128, 0, stream>>>(pooled, pcnt, fc1w, fc1b, fc2w, fc2b, (float*)d_out);
}

// Round 2
// 467.610 us; speedup vs baseline: 2.0959x; 2.0959x over previous
//
#include <hip/hip_runtime.h>

#define N_NODES   100000
#define N_EDGES   1600000
#define NUM_GRAPHS 128
#define HID       64

// ---------------------------------------------------------------- utilities

__device__ __forceinline__ int wave_incl_scan(int v, int lane) {
  #pragma unroll
  for (int d = 1; d < 64; d <<= 1) {
    int t = __shfl_up(v, d, 64);
    if (lane >= d) v += t;
  }
  return v;
}

__global__ void k_zero(int* __restrict__ p, int n) {
  int i = blockIdx.x * blockDim.x + threadIdx.x;
  if (i < n) p[i] = 0;
}

// ---------------------------------------------------------------- CSR build

__global__ void k_count(const int* __restrict__ dst, int* __restrict__ counts) {
  int e = blockIdx.x * blockDim.x + threadIdx.x;
  if (e < N_EDGES) atomicAdd(&counts[dst[e]], 1);
}

__global__ void k_dinv(const int* __restrict__ counts, float* __restrict__ dinv) {
  int v = blockIdx.x * blockDim.x + threadIdx.x;
  if (v < N_NODES) dinv[v] = rsqrtf((float)(counts[v] + 1));  // +1 self-loop
}

// Non-monotone CSR allocation: each wave does ONE atomicAdd of its chunk sum,
// then distributes per-node offsets via the inclusive scan.
__global__ void k_alloc(const int* __restrict__ counts, int* __restrict__ row_off,
                        int* __restrict__ total) {
  int i = blockIdx.x * blockDim.x + threadIdx.x;
  int lane = threadIdx.x & 63;
  int c = (i < N_NODES) ? counts[i] : 0;
  int incl = wave_incl_scan(c, lane);
  int base = 0;
  if (lane == 63) base = atomicAdd(total, incl);
  base = __shfl(base, 63, 64);
  if (i < N_NODES) row_off[i] = base + incl - c;
}

__global__ void k_fill(const int* __restrict__ src, const int* __restrict__ dst,
                       const float* __restrict__ dinv, const int* __restrict__ row_off,
                       int* __restrict__ fill_cnt, int2* __restrict__ csr) {
  int e = blockIdx.x * blockDim.x + threadIdx.x;
  if (e >= N_EDGES) return;
  int s = src[e], d = dst[e];
  int p = atomicAdd(&fill_cnt[d], 1);
  int j = row_off[d] + p;
  csr[j] = make_int2(s, __float_as_int(dinv[s] * dinv[d]));
}

// ---------------------------------------------------------------- dense GEMM
// C[100000,64] = A[100000,64] @ W[64,64]. 64-row tile per 256-thread block.

__global__ __launch_bounds__(256) void k_gemm(const float* __restrict__ A,
                                              const float* __restrict__ W,
                                              float* __restrict__ C) {
  __shared__ float sW[64 * 64];
  __shared__ float sA[64][65];  // +1 pad: kills stride-64 bank conflicts
  int tid = threadIdx.x;
  #pragma unroll
  for (int i = tid; i < 1024; i += 256)
    ((float4*)sW)[i] = ((const float4*)W)[i];
  long row0 = (long)blockIdx.x * 64;
  #pragma unroll
  for (int i = tid; i < 1024; i += 256) {
    int r = i >> 4, c4 = (i & 15) << 2;
    long row = row0 + r;
    float4 v = (row < N_NODES) ? *(const float4*)(A + row * 64 + c4)
                               : make_float4(0.f, 0.f, 0.f, 0.f);
    sA[r][c4 + 0] = v.x; sA[r][c4 + 1] = v.y; sA[r][c4 + 2] = v.z; sA[r][c4 + 3] = v.w;
  }
  __syncthreads();
  int tr = (tid >> 4) << 2;   // 4 rows per thread
  int tc = (tid & 15) << 2;   // 4 cols per thread
  float acc[4][4];
  #pragma unroll
  for (int i = 0; i < 4; ++i)
    #pragma unroll
    for (int j = 0; j < 4; ++j) acc[i][j] = 0.f;
  #pragma unroll 8
  for (int k = 0; k < 64; ++k) {
    float4 w = *(const float4*)&sW[k * 64 + tc];
    float a0 = sA[tr + 0][k], a1 = sA[tr + 1][k], a2 = sA[tr + 2][k], a3 = sA[tr + 3][k];
    acc[0][0] += a0 * w.x; acc[0][1] += a0 * w.y; acc[0][2] += a0 * w.z; acc[0][3] += a0 * w.w;
    acc[1][0] += a1 * w.x; acc[1][1] += a1 * w.y; acc[1][2] += a1 * w.z; acc[1][3] += a1 * w.w;
    acc[2][0] += a2 * w.x; acc[2][1] += a2 * w.y; acc[2][2] += a2 * w.z; acc[2][3] += a2 * w.w;
    acc[3][0] += a3 * w.x; acc[3][1] += a3 * w.y; acc[3][2] += a3 * w.z; acc[3][3] += a3 * w.w;
  }
  #pragma unroll
  for (int i = 0; i < 4; ++i) {
    long row = row0 + tr + i;
    if (row < N_NODES)
      *(float4*)(C + row * 64 + tc) = make_float4(acc[i][0], acc[i][1], acc[i][2], acc[i][3]);
  }
}

// ---------------------------------------------------------------- aggregation
// out[v] = relu( dinv[v]^2 * hw[v] + sum_{e: dst=v} norm_e * hw[src_e] + b )
// One wave per node; lane = feature.

__global__ __launch_bounds__(256) void k_agg(const float* __restrict__ hw,
                                             const int* __restrict__ row_off,
                                             const int* __restrict__ counts,
                                             const int2* __restrict__ csr,
                                             const float* __restrict__ dinv,
                                             const float* __restrict__ bias,
                                             float* __restrict__ out) {
  int wid = threadIdx.x >> 6;
  int lane = threadIdx.x & 63;
  int v = blockIdx.x * (blockDim.x >> 6) + wid;
  if (v >= N_NODES) return;
  float dv = dinv[v];
  float acc = dv * dv * hw[(size_t)v * HID + lane];
  int o = row_off[v], c = counts[v];
  int i = 0;
  for (; i + 4 <= c; i += 4) {
    int2 p0 = csr[o + i + 0];
    int2 p1 = csr[o + i + 1];
    int2 p2 = csr[o + i + 2];
    int2 p3 = csr[o + i + 3];
    float h0 = hw[(size_t)p0.x * HID + lane];
    float h1 = hw[(size_t)p1.x * HID + lane];
    float h2 = hw[(size_t)p2.x * HID + lane];
    float h3 = hw[(size_t)p3.x * HID + lane];
    acc += __int_as_float(p0.y) * h0;
    acc += __int_as_float(p1.y) * h1;
    acc += __int_as_float(p2.y) * h2;
    acc += __int_as_float(p3.y) * h3;
  }
  for (; i < c; ++i) {
    int2 p = csr[o + i];
    acc += __int_as_float(p.y) * hw[(size_t)p.x * HID + lane];
  }
  out[(size_t)v * HID + lane] = fmaxf(acc + bias[lane], 0.0f);
}

// ---------------------------------------------------------------- pooling + MLP
// batch is SORTED -> segmented reduction. Each wave owns a 32-node strip,
// accumulates a register partial per lane while the graph id is unchanged,
// flushes one atomic per run boundary. ~200K atomics instead of 6.4M, and
// concurrent waves hit different graphs except at boundaries.

#define POOL_CHUNK 32

__global__ __launch_bounds__(256) void k_pool(const float* __restrict__ h,
                                              const int* __restrict__ batch,
                                              float* __restrict__ pooled,
                                              int* __restrict__ pcnt) {
  int wid = threadIdx.x >> 6, lane = threadIdx.x & 63;
  int w = blockIdx.x * (blockDim.x >> 6) + wid;
  int v0 = w * POOL_CHUNK;
  if (v0 >= N_NODES) return;
  int vend = min(v0 + POOL_CHUNK, N_NODES);
  int g = batch[v0];
  float acc = 0.0f;
  int cnt = 0;
  for (int v = v0; v < vend; ++v) {
    int gv = batch[v];
    if (gv != g) {
      atomicAdd(&pooled[g * HID + lane], acc);
      if (lane == 0) atomicAdd(&pcnt[g], cnt);
      g = gv; acc = 0.0f; cnt = 0;
    }
    acc += h[(size_t)v * HID + lane];
    ++cnt;
  }
  atomicAdd(&pooled[g * HID + lane], acc);
  if (lane == 0) atomicAdd(&pcnt[g], cnt);
}

__global__ void k_mlp(const float* __restrict__ pooled, const int* __restrict__ pcnt,
                      const float* __restrict__ fc1w, const float* __restrict__ fc1b,
                      const float* __restrict__ fc2w, const float* __restrict__ fc2b,
                      float* __restrict__ out) {
  int g = threadIdx.x;
  if (g >= NUM_GRAPHS) return;
  float inv = 1.0f / fmaxf((float)pcnt[g], 1.0f);
  float hid[10];
  #pragma unroll
  for (int j = 0; j < 10; ++j) hid[j] = fc1b[j];
  for (int k = 0; k < HID; ++k) {
    float p = pooled[g * HID + k] * inv;
    #pragma unroll
    for (int j = 0; j < 10; ++j) hid[j] += p * fc1w[k * 10 + j];
  }
  float o = fc2b[0];
  #pragma unroll
  for (int j = 0; j < 10; ++j) o += fmaxf(hid[j], 0.0f) * fc2w[j];
  out[g] = o;
}

// ---------------------------------------------------------------- launch

extern "C" void kernel_launch(void* const* d_in, const int* in_sizes, int n_in,
                              void* d_out, int out_size, void* d_ws, size_t ws_size,
                              hipStream_t stream) {
  const float* x    = (const float*)d_in[0];
  const int*   ei   = (const int*)d_in[1];      // [2, E]
  const int*   batch= (const int*)d_in[2];
  const float* W1   = (const float*)d_in[3];
  const float* b1   = (const float*)d_in[4];
  const float* W2   = (const float*)d_in[5];
  const float* b2   = (const float*)d_in[6];
  const float* W3   = (const float*)d_in[7];
  const float* b3   = (const float*)d_in[8];
  const float* fc1w = (const float*)d_in[9];
  const float* fc1b = (const float*)d_in[10];
  const float* fc2w = (const float*)d_in[11];
  const float* fc2b = (const float*)d_in[12];

  const int* e_src = ei;
  const int* e_dst = ei + N_EDGES;

  // workspace layout
  char* ws = (char*)d_ws;
  int* counts   = (int*)ws;                  // [100000]
  int* fill_cnt = counts + 100000;           // [100000]
  int* total    = counts + 200000;           // [1] (+pad to 64)
  int* pcnt     = counts + 200064;           // [128]
  float* pooled = (float*)(counts + 200192); // [8192]
  const int ZERO_N = 208384;                 // everything above, in ints
  size_t off = (size_t)ZERO_N * 4;
  auto alignup = [](size_t o, size_t a) { return (o + a - 1) / a * a; };
  off = alignup(off, 256);
  float* dinv = (float*)(ws + off);  off += (size_t)N_NODES * 4;   off = alignup(off, 256);
  int* row_off = (int*)(ws + off);   off += (size_t)N_NODES * 4;   off = alignup(off, 256);
  int2* csr = (int2*)(ws + off);     off += (size_t)N_EDGES * 8;   off = alignup(off, 256);
  float* h_a = (float*)(ws + off);   off += (size_t)N_NODES * HID * 4; off = alignup(off, 256);
  float* h_b = (float*)(ws + off);   off += (size_t)N_NODES * HID * 4;
  (void)ws_size; (void)in_sizes; (void)n_in; (void)out_size;

  const int TB = 256;
  // CSR build
  k_zero <<<(ZERO_N + TB - 1) / TB, TB, 0, stream>>>(counts, ZERO_N);
  k_count<<<(N_EDGES + TB - 1) / TB, TB, 0, stream>>>(e_dst, counts);
  k_dinv <<<(N_NODES + TB - 1) / TB, TB, 0, stream>>>(counts, dinv);
  k_alloc<<<(N_NODES + TB - 1) / TB, TB, 0, stream>>>(counts, row_off, total);
  k_fill <<<(N_EDGES + TB - 1) / TB, TB, 0, stream>>>(e_src, e_dst, dinv, row_off, fill_cnt, csr);

  const int GEMM_GRID = (N_NODES + 63) / 64;       // 1563
  const int AGG_GRID  = (N_NODES + 3) / 4;         // 25000 (4 waves/block)

  // layer 1
  k_gemm<<<GEMM_GRID, TB, 0, stream>>>(x, W1, h_a);
  k_agg <<<AGG_GRID, TB, 0, stream>>>(h_a, row_off, counts, csr, dinv, b1, h_b);
  // layer 2
  k_gemm<<<GEMM_GRID, TB, 0, stream>>>(h_b, W2, h_a);
  k_agg <<<AGG_GRID, TB, 0, stream>>>(h_a, row_off, counts, csr, dinv, b2, h_b);
  // layer 3
  k_gemm<<<GEMM_GRID, TB, 0, stream>>>(h_b, W3, h_a);
  k_agg <<<AGG_GRID, TB, 0, stream>>>(h_a, row_off, counts, csr, dinv, b3, h_b);

  // pool + MLP
  const int POOL_GRID = ((N_NODES + POOL_CHUNK - 1) / POOL_CHUNK + 3) / 4;
  k_pool<<<POOL_GRID, TB, 0, stream>>>(h_b, batch, pooled, pcnt);
  k_mlp <<<1, 128, 0, stream>>>(pooled, pcnt, fc1w, fc1b, fc2w, fc2b, (float*)d_out);
}